// Round 1
// baseline (219.212 us; speedup 1.0000x reference)
//
#include <hip/hip_runtime.h>

#define C 128
#define H 128
#define W 128
#define HW (H*W)

// K1: g[b,h,w] = sum_c feat[b,c,h,w] * w_cls[c]
__global__ __launch_bounds__(512) void g_kernel(
    const float* __restrict__ feat, const float* __restrict__ wc,
    float* __restrict__ g)
{
    const int blk  = blockIdx.x;        // b*H + h
    const int b    = blk >> 7;
    const int h    = blk & (H - 1);
    const int tid  = threadIdx.x;
    const int cg   = tid >> 6;          // 0..7 channel group (16 ch each)
    const int lane = tid & 63;

    const float* base = feat + ((size_t)(b * C + cg * 16)) * HW + h * W + 2 * lane;
    float ax = 0.f, ay = 0.f;
#pragma unroll
    for (int c = 0; c < 16; ++c) {
        const float2 f = *(const float2*)(base + (size_t)c * HW);
        const float wv = wc[cg * 16 + c];
        ax = fmaf(f.x, wv, ax);
        ay = fmaf(f.y, wv, ay);
    }
    __shared__ float gred[8][W];
    gred[cg][2 * lane]     = ax;
    gred[cg][2 * lane + 1] = ay;
    __syncthreads();
    if (tid < W) {
        float s = 0.f;
#pragma unroll
        for (int k = 0; k < 8; ++k) s += gred[k][tid];
        g[(size_t)blk * W + tid] = s;
    }
}

// K2: corr(25 dilated neighbors) -> relu -> softmax -> sum attn*g -> +bias
__global__ __launch_bounds__(512) void prop_kernel(
    const float* __restrict__ feat, const float* __restrict__ g,
    const float* __restrict__ bc, float* __restrict__ out)
{
    const int blk  = blockIdx.x;        // b*H + h
    const int b    = blk >> 7;
    const int h    = blk & (H - 1);
    const int tid  = threadIdx.x;
    const int cg   = tid >> 6;          // 8 channel groups x 16 channels
    const int lane = tid & 63;
    const int w0   = 2 * lane;          // lane owns pixels (w0, w0+1)

    __shared__ float corr[25][W];
    for (int i = tid; i < 25 * W; i += 512) (&corr[0][0])[i] = 0.f;
    __syncthreads();

    float accx[25], accy[25];
#pragma unroll
    for (int n = 0; n < 25; ++n) { accx[n] = 0.f; accy[n] = 0.f; }

    const float* fb = feat + ((size_t)(b * C + cg * 16)) * HW;

#pragma unroll 1
    for (int c = 0; c < 16; ++c) {
        const float* fp = fb + (size_t)c * HW;
        float ldx[25], ldy[25];
#pragma unroll
        for (int i = 0; i < 5; ++i) {
            const int r   = h + 2 * i - 4;
            const bool rok = ((unsigned)r < (unsigned)H);
#pragma unroll
            for (int j = 0; j < 5; ++j) {
                const int col = w0 + 2 * j - 4;       // even -> aligned float2
                float2 v = make_float2(0.f, 0.f);
                if (rok && ((unsigned)col < (unsigned)W))
                    v = *(const float2*)(fp + r * W + col);
                ldx[i * 5 + j] = v.x;
                ldy[i * 5 + j] = v.y;
            }
        }
        const float cx = ldx[12], cy = ldy[12];       // (di,dj)=(0,0) is center
#pragma unroll
        for (int n = 0; n < 25; ++n) {
            accx[n] = fmaf(cx, ldx[n], accx[n]);
            accy[n] = fmaf(cy, ldy[n], accy[n]);
        }
    }

#pragma unroll
    for (int n = 0; n < 25; ++n) {
        atomicAdd(&corr[n][w0],     accx[n]);
        atomicAdd(&corr[n][w0 + 1], accy[n]);
    }
    __syncthreads();

    if (tid < W) {
        const int w = tid;
        float v[25];
        float m = 0.f;                                // all relu'd vals >= 0
#pragma unroll
        for (int n = 0; n < 25; ++n) {
            v[n] = fmaxf(corr[n][w], 0.f);
            m = fmaxf(m, v[n]);
        }
        float s = 0.f, num = 0.f;
#pragma unroll
        for (int n = 0; n < 25; ++n) {
            const float en = __expf(v[n] - m);
            s += en;
            const int r  = h + 2 * (n / 5) - 4;
            const int cc = w + 2 * (n % 5) - 4;
            const float gv = (((unsigned)r < (unsigned)H) && ((unsigned)cc < (unsigned)W))
                               ? g[((size_t)(b * H + r)) * W + cc] : 0.f;
            num = fmaf(en, gv, num);
        }
        out[(size_t)blk * W + w] = num / s + bc[0];
    }
}

extern "C" void kernel_launch(void* const* d_in, const int* in_sizes, int n_in,
                              void* d_out, int out_size, void* d_ws, size_t ws_size,
                              hipStream_t stream) {
    const float* feat = (const float*)d_in[0];
    const float* wcls = (const float*)d_in[1];
    const float* bcls = (const float*)d_in[2];
    float* outp = (float*)d_out;
    float* g    = (float*)d_ws;        // 4*128*128 floats = 256 KB scratch

    g_kernel<<<dim3(4 * H), dim3(512), 0, stream>>>(feat, wcls, g);
    prop_kernel<<<dim3(4 * H), dim3(512), 0, stream>>>(feat, g, bcls, outp);
}

// Round 2
// 179.205 us; speedup vs baseline: 1.2232x; 1.2232x over previous
//
#include <hip/hip_runtime.h>

#define C 128
#define H 128
#define W 128
#define HW (H*W)

// K1: g[b,h,w] = sum_c feat[b,c,h,w] * w_cls[c]   (streaming dot over channels)
__global__ __launch_bounds__(512) void g_kernel(
    const float* __restrict__ feat, const float* __restrict__ wc,
    float* __restrict__ g)
{
    const int blk = blockIdx.x;          // b*64 + seg
    const int b   = blk >> 6;
    const int seg = blk & 63;
    const int tid = threadIdx.x;
    const int hh  = tid >> 8;            // channel half: 0..1
    const int px  = seg * 256 + (tid & 255);

    const float* fp = feat + ((size_t)(b * C + hh * 64)) * HW + px;
    float a = 0.f;
#pragma unroll 8
    for (int c = 0; c < 64; ++c)
        a = fmaf(fp[(size_t)c * HW], wc[hh * 64 + c], a);

    __shared__ float red[2][256];
    red[hh][tid & 255] = a;
    __syncthreads();
    if (tid < 256)
        g[(size_t)b * HW + px] = red[0][tid] + red[1][tid];
}

// K2: corr(25 dilated taps) -> relu -> softmax -> sum attn*g -> +bias
// block = (b, 2 output rows); lane owns 4 px (float4); wave owns 16 channels.
__global__ __launch_bounds__(512, 1) void prop_kernel(
    const float* __restrict__ feat, const float* __restrict__ g,
    const float* __restrict__ bc, float* __restrict__ out)
{
    __shared__ float corr_s[25 * 64 * 5];   // [n][lane][p], (5*lane+p)%32 -> conflict-free

    const int blk  = blockIdx.x;         // b*64 + hblk
    const int b    = blk >> 6;
    const int h0   = (blk & 63) * 2;
    const int tid  = threadIdx.x;
    const int cg   = tid >> 6;           // wave id = channel group (16 ch)
    const int lane = tid & 63;
    const int half = lane >> 5;          // 0 -> row h0, 1 -> row h0+1
    const int cb   = (lane & 31) * 4;    // base col of this lane's 4 px
    const int r    = h0 + half;

    for (int i = tid; i < 25 * 64 * 5; i += 512) corr_s[i] = 0.f;

    // per-lane clamped tap offsets (constant over channels)
    int roff[5];  bool rok[5];
#pragma unroll
    for (int i = 0; i < 5; ++i) {
        const int rt = r - 4 + 2 * i;
        rok[i] = ((unsigned)rt < (unsigned)H);
        const int rc = rt < 0 ? 0 : (rt > H - 1 ? H - 1 : rt);
        roff[i] = rc * W;
    }
    int coff[3];
#pragma unroll
    for (int s = 0; s < 3; ++s) {
        const int cs = cb - 4 + 4 * s;
        coff[s] = cs < 0 ? 0 : (cs > W - 4 ? W - 4 : cs);
    }
    int toff[5][3];
#pragma unroll
    for (int i = 0; i < 5; ++i)
#pragma unroll
        for (int s = 0; s < 3; ++s) toff[i][s] = roff[i] + coff[s];

    const float* fb = feat + ((size_t)(b * C + cg * 16)) * HW;

    float acc[100];
#pragma unroll
    for (int k = 0; k < 100; ++k) acc[k] = 0.f;

#pragma unroll 1
    for (int c = 0; c < 16; ++c) {
        const float* fp = fb + (size_t)c * HW;
        float rows[5][12];
#pragma unroll
        for (int i = 0; i < 5; ++i) {
#pragma unroll
            for (int s = 0; s < 3; ++s)
                *(float4*)&rows[i][4 * s] = *(const float4*)(fp + toff[i][s]);
        }
        // center px values: row 2 (i=2), cols cb..cb+3 == rows[2][4..7]
        float ctr[4];
#pragma unroll
        for (int p = 0; p < 4; ++p) ctr[p] = rows[2][4 + p];
#pragma unroll
        for (int i = 0; i < 5; ++i)
#pragma unroll
            for (int j = 0; j < 5; ++j)
#pragma unroll
                for (int p = 0; p < 4; ++p)
                    acc[(i * 5 + j) * 4 + p] =
                        fmaf(ctr[p], rows[i][p + 2 * j], acc[(i * 5 + j) * 4 + p]);
    }
    __syncthreads();  // corr_s zero-init complete before atomics (cheap, once)

    // mask invalid taps once, reduce across the 8 waves
#pragma unroll
    for (int i = 0; i < 5; ++i)
#pragma unroll
        for (int j = 0; j < 5; ++j)
#pragma unroll
            for (int p = 0; p < 4; ++p) {
                const int n  = i * 5 + j;
                const bool ok = rok[i] && ((unsigned)(cb + p + 2 * j - 4) < (unsigned)W);
                const float v = ok ? acc[n * 4 + p] : 0.f;
                atomicAdd(&corr_s[(n * 64 + lane) * 5 + p], v);
            }
    __syncthreads();

    if (tid < 256) {
        const int rr = h0 + (tid >> 7);
        const int w  = tid & 127;
        const int pl = ((tid >> 7) << 5) + (w >> 2);
        const int p  = w & 3;
        float v[25], m = 0.f;
#pragma unroll
        for (int n = 0; n < 25; ++n) {
            v[n] = fmaxf(corr_s[(n * 64 + pl) * 5 + p], 0.f);
            m = fmaxf(m, v[n]);
        }
        float s = 0.f, num = 0.f;
#pragma unroll
        for (int i = 0; i < 5; ++i)
#pragma unroll
            for (int j = 0; j < 5; ++j) {
                const float e = __expf(v[i * 5 + j] - m);
                s += e;
                const int rt = rr - 4 + 2 * i;
                const int wt = w  - 4 + 2 * j;
                const float gv = (((unsigned)rt < (unsigned)H) && ((unsigned)wt < (unsigned)W))
                                   ? g[((size_t)(b * H + rt)) * W + wt] : 0.f;
                num = fmaf(e, gv, num);
            }
        out[((size_t)(b * H + rr)) * W + w] = num / s + bc[0];
    }
}

extern "C" void kernel_launch(void* const* d_in, const int* in_sizes, int n_in,
                              void* d_out, int out_size, void* d_ws, size_t ws_size,
                              hipStream_t stream) {
    const float* feat = (const float*)d_in[0];
    const float* wcls = (const float*)d_in[1];
    const float* bcls = (const float*)d_in[2];
    float* outp = (float*)d_out;
    float* g    = (float*)d_ws;          // 4*128*128 floats = 256 KB scratch

    g_kernel<<<dim3(4 * 64), dim3(512), 0, stream>>>(feat, wcls, g);
    prop_kernel<<<dim3(4 * 64), dim3(512), 0, stream>>>(feat, g, bcls, outp);
}